// Round 3
// baseline (99.253 us; speedup 1.0000x reference)
//
#include <hip/hip_runtime.h>
#include <hip/hip_bf16.h>
#include <stdint.h>

// PositionalSAE on MI355X — round 3.
// Counted-vmcnt deep pipeline (m201/T3+T4 pattern): 3 LDS buffers, 2-deep
// W prefetch via global_load_lds, 1-deep A register prefetch, raw s_barrier
// + manual s_waitcnt vmcnt(N) (never 0 in steady state).

#define D_IN   2048
#define CHUNK  4096
#define RS     32
#define LN_EPS 1e-5f

typedef __attribute__((ext_vector_type(8))) short bf16x8;
typedef __attribute__((ext_vector_type(4))) float f32x4;

#define AS1 __attribute__((address_space(1)))
#define AS3 __attribute__((address_space(3)))

__device__ __forceinline__ void gload_lds16(const float* g, float* l) {
  __builtin_amdgcn_global_load_lds((const AS1 unsigned int*)g,
                                   (AS3 unsigned int*)l, 16, 0, 0);
}

__device__ __forceinline__ unsigned short f2bf(float f) {
  unsigned int u = __float_as_uint(f);
  u += 0x7fffu + ((u >> 16) & 1u);
  return (unsigned short)(u >> 16);
}

// ---------------------------------------------------------------------------
// Kernel 1: prep. xfrag[r][mt][kt(64)][lane(64)][8] bf16, MFMA A-frag order:
//   element j = x[m = mt*16 + (lane&15)][k = kt*32 + (lane>>4)*8 + j]
// x = acts + pos_emb[r] - b_dec. Also zeroes the 256-float LN stats.
// ---------------------------------------------------------------------------
__global__ __launch_bounds__(256) void prep_kernel(
    const float* __restrict__ acts, const float* __restrict__ pos,
    const float* __restrict__ bdec, unsigned short* __restrict__ xfrag,
    float* __restrict__ stats) {
  unsigned tid = blockIdx.x * 256u + threadIdx.x;
  if (blockIdx.x == 0) stats[threadIdx.x] = 0.0f;
  unsigned lane = tid & 63u, kt = (tid >> 6) & 63u, mt = (tid >> 12) & 1u, r = tid >> 13;
  unsigned m  = mt * 16 + (lane & 15u);
  unsigned k0 = kt * 32 + (lane >> 4) * 8;
  const float* ap = acts + (size_t)(r * RS + m) * D_IN + k0;
  const float* pp = pos  + (size_t)r * D_IN + k0;
  const float* bp = bdec + k0;
  bf16x8 v;
#pragma unroll
  for (int j = 0; j < 8; ++j) v[j] = (short)f2bf(ap[j] + pp[j] - bp[j]);
  *reinterpret_cast<bf16x8*>(xfrag + (size_t)tid * 8) = v;
}

// ---------------------------------------------------------------------------
// Kernel 2: encoder. grid = 4r x 128nt (BN=32) = 512 blocks, 8 waves
// (nsub = w>>2 picks 16-col subtile, kq = w&3 splits each 128-row K-step).
// 16 K-steps, 3-buffer pipeline, counted vmcnt(2).
// ---------------------------------------------------------------------------
__global__ __launch_bounds__(512) void enc_kernel(
    const unsigned short* __restrict__ xfrag, const float* __restrict__ Wenc,
    const float* __restrict__ benc, float* __restrict__ pre,
    float* __restrict__ stats) {
  const unsigned r = blockIdx.x >> 7, nt = blockIdx.x & 127u;
  const unsigned n0 = nt * 32;
  const unsigned w = threadIdx.x >> 6, lane = threadIdx.x & 63u;
  const unsigned nsub = w >> 2, kq = w & 3u;
  const unsigned col = lane & 15u, g = lane >> 4;

  __shared__ float tiles[3][128 * 32];          // 48 KiB
  __shared__ float red[3][2][2][64][4];         // 24 KiB

  const unsigned srow = lane >> 3;
  const unsigned scol = (lane & 7u) * 4u;
  const float* gbase = Wenc + (size_t)r * D_IN * CHUNK + n0 + scol;
  const unsigned short* xa = xfrag + (size_t)r * 2 * 64 * 64 * 8;

  f32x4 acc0 = {0.f,0.f,0.f,0.f}, acc1 = acc0;

  auto stageW = [&](unsigned t, unsigned b) {
#pragma unroll
    for (int l = 0; l < 2; ++l) {
      const float* gp = gbase + (size_t)(t * 128 + w * 16 + l * 8 + srow) * CHUNK;
      gload_lds16(gp, &tiles[b][(w * 2 + l) * 256]);
    }
  };

  bf16x8 a0c, a1c, a0n, a1n;
  stageW(0, 0);
  {
    unsigned kt = kq;
    a0c = *(const bf16x8*)(xa + ((size_t)kt * 64 + lane) * 8);
    a1c = *(const bf16x8*)(xa + ((size_t)(64 + kt) * 64 + lane) * 8);
  }
  stageW(1, 1);

  for (unsigned s = 0; s < 16; ++s) {
    if (s < 15) asm volatile("s_waitcnt vmcnt(2)" ::: "memory");
    else        asm volatile("s_waitcnt vmcnt(0)" ::: "memory");
    __builtin_amdgcn_s_barrier();
    __builtin_amdgcn_sched_barrier(0);
    if (s < 15) {                      // A prefetch FIRST (vmcnt order matters)
      unsigned kt = (s + 1) * 4 + kq;
      a0n = *(const bf16x8*)(xa + ((size_t)kt * 64 + lane) * 8);
      a1n = *(const bf16x8*)(xa + ((size_t)(64 + kt) * 64 + lane) * 8);
    }
    __builtin_amdgcn_sched_barrier(0);
    if (s < 14) stageW(s + 2, (s + 2) % 3);
    const float* tb = &tiles[s % 3][(kq * 32 + g * 8) * 32 + nsub * 16 + col];
    bf16x8 bfrag;
#pragma unroll
    for (int j = 0; j < 8; ++j) bfrag[j] = (short)f2bf(tb[j * 32]);
    acc0 = __builtin_amdgcn_mfma_f32_16x16x32_bf16(a0c, bfrag, acc0, 0, 0, 0);
    acc1 = __builtin_amdgcn_mfma_f32_16x16x32_bf16(a1c, bfrag, acc1, 0, 0, 0);
    a0c = a0n; a1c = a1n;
  }

  if (kq != 0) {
#pragma unroll
    for (int i = 0; i < 4; ++i) {
      red[kq - 1][nsub][0][lane][i] = acc0[i];
      red[kq - 1][nsub][1][lane][i] = acc1[i];
    }
  }
  __syncthreads();
  if (kq == 0) {
    for (int q = 0; q < 3; ++q)
#pragma unroll
      for (int i = 0; i < 4; ++i) {
        acc0[i] += red[q][nsub][0][lane][i];
        acc1[i] += red[q][nsub][1][lane][i];
      }
    const unsigned nc = n0 + nsub * 16 + col;
    float bias = benc[(size_t)r * CHUNK + nc];
#pragma unroll
    for (int mt = 0; mt < 2; ++mt) {
#pragma unroll
      for (int i = 0; i < 4; ++i) {
        float v = (mt ? acc1[i] : acc0[i]) + bias;
        unsigned row = mt * 16 + g * 4 + i;
        pre[(size_t)(r * RS + row) * CHUNK + nc] = v;
        float s2 = v, q2 = v * v;
#pragma unroll
        for (int off = 1; off < 16; off <<= 1) {
          s2 += __shfl_xor(s2, off, 16);
          q2 += __shfl_xor(q2, off, 16);
        }
        if (col == 0) {
          atomicAdd(&stats[r * 32 + row], s2);
          atomicAdd(&stats[128 + r * 32 + row], q2);
        }
      }
    }
  }
}

// ---------------------------------------------------------------------------
// Kernel 3: finish LayerNorm + ReLU -> decoder A-frags bf16.
// featfrag[r][mt][kt(128)][lane][8]
// ---------------------------------------------------------------------------
__global__ __launch_bounds__(256) void lnpack_kernel(
    const float* __restrict__ pre, const float* __restrict__ stats,
    const float* __restrict__ gamma, const float* __restrict__ beta,
    unsigned short* __restrict__ featfrag) {
  unsigned tid = blockIdx.x * 256u + threadIdx.x;
  unsigned lane = tid & 63u, kt = (tid >> 6) & 127u, mt = (tid >> 13) & 1u, r = tid >> 14;
  unsigned m  = mt * 16 + (lane & 15u);
  unsigned s0 = kt * 32 + (lane >> 4) * 8;
  float mu  = stats[r * 32 + m] * (1.f / CHUNK);
  float var = stats[128 + r * 32 + m] * (1.f / CHUNK) - mu * mu;
  float rsd = rsqrtf(var + LN_EPS);
  const float* pp = pre   + (size_t)(r * RS + m) * CHUNK + s0;
  const float* gp = gamma + (size_t)r * CHUNK + s0;
  const float* bp = beta  + (size_t)r * CHUNK + s0;
  bf16x8 v;
#pragma unroll
  for (int j = 0; j < 8; ++j) {
    float x = (pp[j] - mu) * rsd * gp[j] + bp[j];
    v[j] = (short)f2bf(fmaxf(x, 0.f));
  }
  *reinterpret_cast<bf16x8*>(featfrag + (size_t)tid * 8) = v;
}

// ---------------------------------------------------------------------------
// Kernel 4: decoder. grid = 4r x 128nt (BN=16) = 512 blocks, 8 waves
// (mt = w>>2 picks 16-row A tile, kq = w&3 splits each 128-row K-step).
// Full K=4096 in 32 steps; writes d_out directly (+b_dec).
// ---------------------------------------------------------------------------
__global__ __launch_bounds__(512) void dec_kernel(
    const unsigned short* __restrict__ featfrag, const float* __restrict__ Wdec,
    const float* __restrict__ bdec, float* __restrict__ out) {
  const unsigned r = blockIdx.x >> 7, nt = blockIdx.x & 127u;
  const unsigned n0 = nt * 16;
  const unsigned w = threadIdx.x >> 6, lane = threadIdx.x & 63u;
  const unsigned mt = w >> 2, kq = w & 3u;
  const unsigned col = lane & 15u, g = lane >> 4;

  __shared__ float tiles[3][128 * 16];          // 24 KiB
  __shared__ float red[3][2][64][4];            // 6 KiB

  const unsigned srow = lane >> 2;              // 0..15
  const unsigned scol = (lane & 3u) * 4u;
  const float* gbase = Wdec + (size_t)r * CHUNK * D_IN + n0 + scol;
  const unsigned short* fa = featfrag + (size_t)r * 2 * 128 * 64 * 8;

  f32x4 acc = {0.f,0.f,0.f,0.f};

  auto stageW = [&](unsigned t, unsigned b) {
    const float* gp = gbase + (size_t)(t * 128 + w * 16 + srow) * D_IN;
    gload_lds16(gp, &tiles[b][w * 256]);
  };

  bf16x8 ac, an;
  stageW(0, 0);
  ac = *(const bf16x8*)(fa + ((size_t)(mt * 128 + kq) * 64 + lane) * 8);
  stageW(1, 1);

  for (unsigned s = 0; s < 32; ++s) {
    if (s < 31) asm volatile("s_waitcnt vmcnt(1)" ::: "memory");
    else        asm volatile("s_waitcnt vmcnt(0)" ::: "memory");
    __builtin_amdgcn_s_barrier();
    __builtin_amdgcn_sched_barrier(0);
    if (s < 31) {
      unsigned kt = (s + 1) * 4 + kq;
      an = *(const bf16x8*)(fa + ((size_t)(mt * 128 + kt) * 64 + lane) * 8);
    }
    __builtin_amdgcn_sched_barrier(0);
    if (s < 30) stageW(s + 2, (s + 2) % 3);
    const float* tb = &tiles[s % 3][(kq * 32 + g * 8) * 16 + col];
    bf16x8 bfrag;
#pragma unroll
    for (int j = 0; j < 8; ++j) bfrag[j] = (short)f2bf(tb[j * 16]);
    acc = __builtin_amdgcn_mfma_f32_16x16x32_bf16(ac, bfrag, acc, 0, 0, 0);
    ac = an;
  }

  if (kq != 0) {
#pragma unroll
    for (int i = 0; i < 4; ++i) red[kq - 1][mt][lane][i] = acc[i];
  }
  __syncthreads();
  if (kq == 0) {
    for (int q = 0; q < 3; ++q)
#pragma unroll
      for (int i = 0; i < 4; ++i) acc[i] += red[q][mt][lane][i];
    float bias = bdec[n0 + col];
#pragma unroll
    for (int i = 0; i < 4; ++i) {
      unsigned row = mt * 16 + g * 4 + i;
      out[(size_t)(r * RS + row) * D_IN + n0 + col] = acc[i] + bias;
    }
  }
}

// ---------------------------------------------------------------------------
extern "C" void kernel_launch(void* const* d_in, const int* in_sizes, int n_in,
                              void* d_out, int out_size, void* d_ws, size_t ws_size,
                              hipStream_t stream) {
  const float* acts = (const float*)d_in[0];
  const float* Wenc = (const float*)d_in[1];
  const float* benc = (const float*)d_in[2];
  const float* bdec = (const float*)d_in[3];
  const float* pos  = (const float*)d_in[4];
  const float* lnw  = (const float*)d_in[5];
  const float* lnb  = (const float*)d_in[6];
  const float* Wdec = (const float*)d_in[7];
  float* out = (float*)d_out;

  char* ws = (char*)d_ws;
  float* stats            = (float*)ws;                                   // 1 KiB
  unsigned short* xfrag   = (unsigned short*)(ws + 1024);                 // 512 KiB
  float* pre              = (float*)(ws + 1024 + 512 * 1024);             // 2 MiB
  unsigned short* featfrg = (unsigned short*)(ws + 1024 + 512 * 1024 + 2 * 1024 * 1024); // 1 MiB

  prep_kernel  <<<128, 256, 0, stream>>>(acts, pos, bdec, xfrag, stats);
  enc_kernel   <<<512, 512, 0, stream>>>(xfrag, Wenc, benc, pre, stats);
  lnpack_kernel<<<256, 256, 0, stream>>>(pre, stats, lnw, lnb, featfrg);
  dec_kernel   <<<512, 512, 0, stream>>>(featfrg, Wdec, bdec, out);
}